// Round 1
// baseline (176.826 us; speedup 1.0000x reference)
//
#include <hip/hip_runtime.h>

// ContrastiveLoss: loss = sum_n [ log(sum_j exp(2*<ne_n,ne_j>)) - 2*<ne_n,nt_n> ] / (2N)
// N=8192, D=512, POS_W=NEG_W=0.5.
// Pipeline:
//   k_norm : normalize rows of emb/tgt, write ne as bf16 (ws), pos[n] (ws)
//   k_gemm : 128x128-tile NT GEMM via mfma_f32_16x16x32_bf16, fused exp + row-sum
//            -> partial[128][8192] (per block-col, per row), no atomics
//   k_final: S_n = sum_p partial[p][n]; reduce log(S)-2*pos into scalar d_out

typedef __attribute__((ext_vector_type(8))) short short8;
typedef __attribute__((ext_vector_type(4))) float floatx4;

#define N 8192
#define D 512

__device__ __forceinline__ unsigned short f2bf(float f) {
    unsigned int u = __float_as_uint(f);
    unsigned int r = u + 0x7fffu + ((u >> 16) & 1u);   // round-to-nearest-even
    return (unsigned short)(r >> 16);
}

__global__ __launch_bounds__(256) void k_norm(const float* __restrict__ emb,
                                              const float* __restrict__ tgt,
                                              unsigned short* __restrict__ neb,
                                              float* __restrict__ pos) {
    int wave = threadIdx.x >> 6;
    int lane = threadIdx.x & 63;
    int row  = blockIdx.x * 4 + wave;          // one wave per row
    const float4* e4 = (const float4*)(emb + (size_t)row * D) + lane * 2;
    const float4* t4 = (const float4*)(tgt + (size_t)row * D) + lane * 2;
    float4 e0 = e4[0], e1 = e4[1];
    float4 t0 = t4[0], t1 = t4[1];
    float ee = e0.x*e0.x + e0.y*e0.y + e0.z*e0.z + e0.w*e0.w
             + e1.x*e1.x + e1.y*e1.y + e1.z*e1.z + e1.w*e1.w;
    float tt = t0.x*t0.x + t0.y*t0.y + t0.z*t0.z + t0.w*t0.w
             + t1.x*t1.x + t1.y*t1.y + t1.z*t1.z + t1.w*t1.w;
    float et = e0.x*t0.x + e0.y*t0.y + e0.z*t0.z + e0.w*t0.w
             + e1.x*t1.x + e1.y*t1.y + e1.z*t1.z + e1.w*t1.w;
    #pragma unroll
    for (int off = 1; off < 64; off <<= 1) {
        ee += __shfl_xor(ee, off);
        tt += __shfl_xor(tt, off);
        et += __shfl_xor(et, off);
    }
    float se = fmaxf(sqrtf(ee), 1e-12f);
    float st = fmaxf(sqrtf(tt), 1e-12f);
    if (lane == 0) pos[row] = et / (se * st);
    float inv = 1.0f / se;
    unsigned short v0 = f2bf(e0.x*inv), v1 = f2bf(e0.y*inv), v2 = f2bf(e0.z*inv), v3 = f2bf(e0.w*inv);
    unsigned short v4 = f2bf(e1.x*inv), v5 = f2bf(e1.y*inv), v6 = f2bf(e1.z*inv), v7 = f2bf(e1.w*inv);
    uint4 pk;
    pk.x = (unsigned)v0 | ((unsigned)v1 << 16);
    pk.y = (unsigned)v2 | ((unsigned)v3 << 16);
    pk.z = (unsigned)v4 | ((unsigned)v5 << 16);
    pk.w = (unsigned)v6 | ((unsigned)v7 << 16);
    ((uint4*)(neb + (size_t)row * D))[lane] = pk;
}

// LDS row stride 48 bf16 = 96 B (16B-aligned, spreads b128 reads evenly over banks)
#define LDSTRIDE 48

__global__ __launch_bounds__(256) void k_gemm(const unsigned short* __restrict__ neb,
                                              float* __restrict__ partial) {
    __shared__ unsigned short sA[128 * LDSTRIDE];
    __shared__ unsigned short sB[128 * LDSTRIDE];
    const int tid  = threadIdx.x;
    const int bj   = blockIdx.x, bi = blockIdx.y;
    const int i0   = bi * 128, j0 = bj * 128;
    const int wave = tid >> 6, lane = tid & 63;
    const int wrow = wave >> 1, wcol = wave & 1;   // 2x2 waves, each 64x64
    const int m16  = lane & 15, quad = lane >> 4;

    floatx4 zero = {0.f, 0.f, 0.f, 0.f};
    floatx4 acc[4][4];
    #pragma unroll
    for (int a = 0; a < 4; ++a)
        #pragma unroll
        for (int b = 0; b < 4; ++b) acc[a][b] = zero;

    for (int kt = 0; kt < D; kt += 32) {
        __syncthreads();
        #pragma unroll
        for (int l = 0; l < 2; ++l) {
            int f = tid + l * 256;            // 0..511
            int r = f >> 2, c = f & 3;        // row 0..127, 8-elem chunk 0..3
            *(uint4*)(&sA[r * LDSTRIDE + c * 8]) =
                *(const uint4*)(neb + ((size_t)(i0 + r) * D + kt + c * 8));
            *(uint4*)(&sB[r * LDSTRIDE + c * 8]) =
                *(const uint4*)(neb + ((size_t)(j0 + r) * D + kt + c * 8));
        }
        __syncthreads();
        short8 af[4], bf[4];
        #pragma unroll
        for (int t = 0; t < 4; ++t) {
            af[t] = *(const short8*)(&sA[(wrow * 64 + t * 16 + m16) * LDSTRIDE + quad * 8]);
            bf[t] = *(const short8*)(&sB[(wcol * 64 + t * 16 + m16) * LDSTRIDE + quad * 8]);
        }
        #pragma unroll
        for (int ti = 0; ti < 4; ++ti)
            #pragma unroll
            for (int tj = 0; tj < 4; ++tj)
                acc[ti][tj] = __builtin_amdgcn_mfma_f32_16x16x32_bf16(af[ti], bf[tj], acc[ti][tj], 0, 0, 0);
    }

    // epilogue: exp(2*c), sum over this block's 128 columns per row, store partial
    const int pslot = bj * 2 + wcol;          // 0..127
    #pragma unroll
    for (int ti = 0; ti < 4; ++ti) {
        #pragma unroll
        for (int r = 0; r < 4; ++r) {
            float s = 0.f;
            #pragma unroll
            for (int tj = 0; tj < 4; ++tj) s += __expf(2.0f * acc[ti][tj][r]);
            #pragma unroll
            for (int off = 1; off < 16; off <<= 1) s += __shfl_xor(s, off);
            if (m16 == 0) {
                int rowg = i0 + wrow * 64 + ti * 16 + quad * 4 + r;
                partial[(size_t)pslot * N + rowg] = s;
            }
        }
    }
}

__global__ __launch_bounds__(256) void k_final(const float* __restrict__ partial,
                                               const float* __restrict__ pos,
                                               float* __restrict__ out) {
    int row = blockIdx.x * 256 + threadIdx.x;
    float S = 0.f;
    #pragma unroll 8
    for (int p = 0; p < 128; ++p) S += partial[(size_t)p * N + row];
    float val = logf(S) - 2.0f * pos[row];
    #pragma unroll
    for (int off = 1; off < 64; off <<= 1) val += __shfl_xor(val, off);
    if ((threadIdx.x & 63) == 0) atomicAdd(out, val * (1.0f / (2.0f * N)));
}

extern "C" void kernel_launch(void* const* d_in, const int* in_sizes, int n_in,
                              void* d_out, int out_size, void* d_ws, size_t ws_size,
                              hipStream_t stream) {
    const float* emb = (const float*)d_in[0];
    const float* tgt = (const float*)d_in[1];
    unsigned short* neb = (unsigned short*)d_ws;                              // 8 MB bf16 ne
    float* pos     = (float*)((char*)d_ws + (size_t)N * D * 2);               // 32 KB
    float* partial = (float*)((char*)d_ws + (size_t)N * D * 2 + (size_t)N * 4); // 4 MB
    float* out = (float*)d_out;

    hipMemsetAsync(out, 0, sizeof(float), stream);
    k_norm<<<N / 4, 256, 0, stream>>>(emb, tgt, neb, pos);
    k_gemm<<<dim3(N / 128, N / 128), 256, 0, stream>>>(neb, partial);
    k_final<<<N / 256, 256, 0, stream>>>(partial, pos, out);
}

// Round 2
// 146.661 us; speedup vs baseline: 1.2057x; 1.2057x over previous
//
#include <hip/hip_runtime.h>

// ContrastiveLoss: loss = sum_n [ log(sum_j exp(2*<ne_n,ne_j>)) - 2*<ne_n,nt_n> ] / (2N)
// N=8192, D=512.
// R1: symmetric GEMM (bi<=bj tiles only, row-sums + col-sums), global_load_lds
//     width=16 staging with XOR-swizzled LDS layout (conflict-free b128 reads),
//     memset folded into k_norm, k_final parallelized 4 threads/row.

typedef __attribute__((ext_vector_type(8))) short short8;
typedef __attribute__((ext_vector_type(4))) float floatx4;

#define N 8192
#define D 512
#define BK 32   // k-step in bf16 elems (64 B = 4 x 16B chunks per row)

__device__ __forceinline__ unsigned short f2bf(float f) {
    unsigned int u = __float_as_uint(f);
    unsigned int r = u + 0x7fffu + ((u >> 16) & 1u);   // round-to-nearest-even
    return (unsigned short)(r >> 16);
}

__device__ __forceinline__ void gload_lds16(const void* g, void* l) {
    __builtin_amdgcn_global_load_lds(
        (const __attribute__((address_space(1))) void*)g,
        (__attribute__((address_space(3))) void*)l, 16, 0, 0);
}

__global__ __launch_bounds__(256) void k_norm(const float* __restrict__ emb,
                                              const float* __restrict__ tgt,
                                              unsigned short* __restrict__ neb,
                                              float* __restrict__ pos,
                                              float* __restrict__ out) {
    if (blockIdx.x == 0 && threadIdx.x == 0) *out = 0.0f;   // replaces memset dispatch
    int wave = threadIdx.x >> 6;
    int lane = threadIdx.x & 63;
    int row  = blockIdx.x * 4 + wave;          // one wave per row
    const float4* e4 = (const float4*)(emb + (size_t)row * D) + lane * 2;
    const float4* t4 = (const float4*)(tgt + (size_t)row * D) + lane * 2;
    float4 e0 = e4[0], e1 = e4[1];
    float4 t0 = t4[0], t1 = t4[1];
    float ee = e0.x*e0.x + e0.y*e0.y + e0.z*e0.z + e0.w*e0.w
             + e1.x*e1.x + e1.y*e1.y + e1.z*e1.z + e1.w*e1.w;
    float tt = t0.x*t0.x + t0.y*t0.y + t0.z*t0.z + t0.w*t0.w
             + t1.x*t1.x + t1.y*t1.y + t1.z*t1.z + t1.w*t1.w;
    float et = e0.x*t0.x + e0.y*t0.y + e0.z*t0.z + e0.w*t0.w
             + e1.x*t1.x + e1.y*t1.y + e1.z*t1.z + e1.w*t1.w;
    #pragma unroll
    for (int off = 1; off < 64; off <<= 1) {
        ee += __shfl_xor(ee, off);
        tt += __shfl_xor(tt, off);
        et += __shfl_xor(et, off);
    }
    float se = fmaxf(sqrtf(ee), 1e-12f);
    float st = fmaxf(sqrtf(tt), 1e-12f);
    if (lane == 0) pos[row] = et / (se * st);
    float inv = 1.0f / se;
    unsigned short v0 = f2bf(e0.x*inv), v1 = f2bf(e0.y*inv), v2 = f2bf(e0.z*inv), v3 = f2bf(e0.w*inv);
    unsigned short v4 = f2bf(e1.x*inv), v5 = f2bf(e1.y*inv), v6 = f2bf(e1.z*inv), v7 = f2bf(e1.w*inv);
    uint4 pk;
    pk.x = (unsigned)v0 | ((unsigned)v1 << 16);
    pk.y = (unsigned)v2 | ((unsigned)v3 << 16);
    pk.z = (unsigned)v4 | ((unsigned)v5 << 16);
    pk.w = (unsigned)v6 | ((unsigned)v7 << 16);
    ((uint4*)(neb + (size_t)row * D))[lane] = pk;
}

// LDS: unpadded [128][BK] bf16 per tile (8 KB), 16B chunk (row,c) stored at
// slot row*4 + (c ^ (row&3))  -> conflict-free ds_read_b128 fragment reads,
// and lane-linear slots for global_load_lds staging.
__global__ __launch_bounds__(256) void k_gemm(const unsigned short* __restrict__ neb,
                                              float* __restrict__ partial) {
    __shared__ unsigned short sA[128 * BK];
    __shared__ unsigned short sB[128 * BK];
    const int bj = blockIdx.x, bi = blockIdx.y;
    if (bi > bj) return;                        // symmetric: upper triangle only
    const int tid  = threadIdx.x;
    const int i0   = bi * 128, j0 = bj * 128;
    const int wave = tid >> 6, lane = tid & 63;
    const int wrow = wave >> 1, wcol = wave & 1;   // 2x2 waves, each 64x64
    const int m16  = lane & 15, quad = lane >> 4;
    const int swz  = quad ^ (m16 & 3);             // lane-constant read swizzle

    // staging: wave w, call c covers LDS slots [w*128 + c*64, +64), lane-linear
    const int slot0 = wave * 128 + lane;
    const int slot1 = slot0 + 64;
    const int r0 = slot0 >> 2, cc0 = (slot0 & 3) ^ (r0 & 3);
    const int r1 = slot1 >> 2, cc1 = (slot1 & 3) ^ (r1 & 3);
    const unsigned short* gA0 = neb + (size_t)(i0 + r0) * D + cc0 * 8;
    const unsigned short* gA1 = neb + (size_t)(i0 + r1) * D + cc1 * 8;
    const unsigned short* gB0 = neb + (size_t)(j0 + r0) * D + cc0 * 8;
    const unsigned short* gB1 = neb + (size_t)(j0 + r1) * D + cc1 * 8;
    unsigned short* lA0 = &sA[(wave * 128) * 8];
    unsigned short* lA1 = &sA[(wave * 128 + 64) * 8];
    unsigned short* lB0 = &sB[(wave * 128) * 8];
    unsigned short* lB1 = &sB[(wave * 128 + 64) * 8];

    floatx4 zero = {0.f, 0.f, 0.f, 0.f};
    floatx4 acc[4][4];
    #pragma unroll
    for (int a = 0; a < 4; ++a)
        #pragma unroll
        for (int b = 0; b < 4; ++b) acc[a][b] = zero;

    for (int kt = 0; kt < D; kt += BK) {
        __syncthreads();
        gload_lds16(gA0 + kt, lA0);
        gload_lds16(gA1 + kt, lA1);
        gload_lds16(gB0 + kt, lB0);
        gload_lds16(gB1 + kt, lB1);
        __syncthreads();
        short8 af[4], bfr[4];
        #pragma unroll
        for (int t = 0; t < 4; ++t) {
            af[t]  = *(const short8*)(&sA[(wrow * 64 + t * 16 + m16) * BK + swz * 8]);
            bfr[t] = *(const short8*)(&sB[(wcol * 64 + t * 16 + m16) * BK + swz * 8]);
        }
        #pragma unroll
        for (int ti = 0; ti < 4; ++ti)
            #pragma unroll
            for (int tj = 0; tj < 4; ++tj)
                acc[ti][tj] = __builtin_amdgcn_mfma_f32_16x16x32_bf16(af[ti], bfr[tj], acc[ti][tj], 0, 0, 0);
    }

    // row-sums: exp(2*c) summed over this block's 128 cols -> slot bj*2+wcol
    const int prow = bj * 2 + wcol;
    #pragma unroll
    for (int ti = 0; ti < 4; ++ti) {
        #pragma unroll
        for (int r = 0; r < 4; ++r) {
            float s = 0.f;
            #pragma unroll
            for (int tj = 0; tj < 4; ++tj) s += __expf(2.0f * acc[ti][tj][r]);
            #pragma unroll
            for (int off = 1; off < 16; off <<= 1) s += __shfl_xor(s, off);
            if (m16 == 0) {
                int rowg = i0 + wrow * 64 + ti * 16 + quad * 4 + r;
                partial[(size_t)prow * N + rowg] = s;
            }
        }
    }
    // col-sums (symmetry: = row-sums of skipped tile (bj,bi)) -> slot bi*2+wrow
    if (bi < bj) {
        const int pcol = bi * 2 + wrow;
        #pragma unroll
        for (int tj = 0; tj < 4; ++tj) {
            float s = 0.f;
            #pragma unroll
            for (int ti = 0; ti < 4; ++ti) {
                #pragma unroll
                for (int r = 0; r < 4; ++r) s += __expf(2.0f * acc[ti][tj][r]);
            }
            s += __shfl_xor(s, 16);
            s += __shfl_xor(s, 32);
            if (quad == 0) {
                int colg = j0 + wcol * 64 + tj * 16 + m16;
                partial[(size_t)pcol * N + colg] = s;
            }
        }
    }
}

__global__ __launch_bounds__(256) void k_final(const float* __restrict__ partial,
                                               const float* __restrict__ pos,
                                               float* __restrict__ out) {
    int tid = threadIdx.x;
    int row = blockIdx.x * 64 + (tid >> 2);
    int sub = tid & 3;
    float S = 0.f;
    #pragma unroll
    for (int i = 0; i < 32; ++i) S += partial[(size_t)(sub + i * 4) * N + row];
    S += __shfl_xor(S, 1);
    S += __shfl_xor(S, 2);
    float val = (sub == 0) ? (logf(S) - 2.0f * pos[row]) : 0.0f;
    #pragma unroll
    for (int off = 4; off < 64; off <<= 1) val += __shfl_xor(val, off);
    if ((tid & 63) == 0) atomicAdd(out, val * (1.0f / (2.0f * N)));
}

extern "C" void kernel_launch(void* const* d_in, const int* in_sizes, int n_in,
                              void* d_out, int out_size, void* d_ws, size_t ws_size,
                              hipStream_t stream) {
    const float* emb = (const float*)d_in[0];
    const float* tgt = (const float*)d_in[1];
    unsigned short* neb = (unsigned short*)d_ws;                                 // 8 MB bf16 ne
    float* pos     = (float*)((char*)d_ws + (size_t)N * D * 2);                  // 32 KB
    float* partial = (float*)((char*)d_ws + (size_t)N * D * 2 + (size_t)N * 4);  // 4 MB
    float* out = (float*)d_out;

    k_norm<<<N / 4, 256, 0, stream>>>(emb, tgt, neb, pos, out);
    k_gemm<<<dim3(N / 128, N / 128), 256, 0, stream>>>(neb, partial);
    k_final<<<N / 64, 256, 0, stream>>>(partial, pos, out);
}